// Round 1
// 663.187 us; speedup vs baseline: 1.0105x; 1.0105x over previous
//
#include <hip/hip_runtime.h>
#include <cstdint>
#include <cstddef>

#define CE 768
#define CD 512
#define NB 64
#define HH 28
#define WW 28
#define HP 30
#define WP 30
#define POS 784            // 28*28
#define M_TOT 50176
#define K_TOT 6912         // 9*768
#define MP 57600           // 64*30*30 padded positions
#define XP_PIX 57728       // MP + slack for staging window overrun

typedef _Float16 f16x8 __attribute__((ext_vector_type(8)));
typedef _Float16 f16x4 __attribute__((ext_vector_type(4)));
typedef float f32x4 __attribute__((ext_vector_type(4)));

// ---------------- kernel 1: weight transpose + cast ----------------
// conv_w [CD][CE][3][3] fp32 -> wT [CD][9*CE] f16 with k = tap*CE + ci
// v2: LDS-staged. float4 coalesced reads -> f16 LDS -> gather -> f16x4 stores.
__global__ void prep_w_kernel(const float* __restrict__ cw, _Float16* __restrict__ wT) {
  __shared__ _Float16 s[K_TOT];          // 13,824 B
  int co = blockIdx.x;
  const float4* src4 = (const float4*)(cw + (size_t)co * K_TOT);
  for (int j = threadIdx.x; j < K_TOT / 4; j += 256) {
    float4 v = src4[j];
    f16x4 o = { (_Float16)v.x, (_Float16)v.y, (_Float16)v.z, (_Float16)v.w };
    *(f16x4*)&s[j * 4] = o;
  }
  __syncthreads();
  _Float16* dst = wT + (size_t)co * K_TOT;
  for (int j4 = threadIdx.x; j4 < K_TOT / 4; j4 += 256) {
    int tap = j4 / 192;                  // 192 = CE/4
    int ci0 = (j4 - tap * 192) * 4;
    f16x4 o = { s[(ci0 + 0) * 9 + tap], s[(ci0 + 1) * 9 + tap],
                s[(ci0 + 2) * 9 + tap], s[(ci0 + 3) * 9 + tap] };
    *(f16x4*)&dst[j4 * 4] = o;
  }
}

// ---------------- kernel 2: fused LN + mask fill -> padded NHWC f16 ----------------
// v2: float4 global loads + in-register 4x4 transpose into a [w][c]-major f16
// tile; gamma/beta/mtok staged in LDS ONCE (was ~43k redundant scalar global
// loads per block); normalize phase reads contiguous f16x8 (ds_read_b128) and
// stores 16 B/lane coalesced.
__global__ void __launch_bounds__(512) ln_fused_kernel(
    const float* __restrict__ bcff, const int* __restrict__ act,
    const float* __restrict__ mtok, const float* __restrict__ gamma,
    const float* __restrict__ beta, _Float16* __restrict__ xp) {
  int b = blockIdx.x / HP, ph = blockIdx.x % HP;
  _Float16* xrow = xp + ((size_t)(b * HP + ph)) * WP * CE;
  const int tid = threadIdx.x;
  if (ph == 0 || ph == HP - 1) {
    uint4* p = (uint4*)xrow;
    uint4 z = make_uint4(0, 0, 0, 0);
    for (int j = tid; j < (WP * CE * 2) / 16; j += 512) p[j] = z;
    return;
  }
  int h = ph - 1;
  {
    uint4 z = make_uint4(0, 0, 0, 0);
    uint4* p0 = (uint4*)xrow;
    uint4* p1 = (uint4*)(xrow + (size_t)(WP - 1) * CE);
    for (int j = tid; j < (CE * 2) / 16; j += 512) { p0[j] = z; p1[j] = z; }
  }

  __shared__ _Float16 tile[WW][776];     // [w][c] major, pad to 776: 43,456 B
  __shared__ float s_gamma[CE], s_beta[CE];   // 6,144 B
  __shared__ _Float16 s_mt[CE];          // 1,536 B
  __shared__ float s_mean[WW], s_rstd[WW];
  __shared__ int s_act[WW];

  // stage per-channel params once (loop-invariant for the whole block)
  for (int c = tid; c < CE; c += 512) {
    s_gamma[c] = gamma[c];
    s_beta[c] = beta[c];
    s_mt[c] = (_Float16)mtok[c];
  }
  if (tid < WW) s_act[tid] = act[b * POS + h * WW + tid];

  // load: 1344 iters, each = 4 float4 (4 channels x 4 pixels) -> 4x4 transpose
  // -> 4 x f16x4 LDS stores (8B aligned since c0 % 4 == 0)
  const float4* src4 = (const float4*)(bcff + ((size_t)b * CE * HH + h) * WW);
  for (int i = tid; i < 1344; i += 512) {
    int cq = i / 7, w4 = i - cq * 7;     // cq 0..191, w4 0..6
    int c0 = cq * 4;
    float4 v0 = src4[(size_t)(c0 + 0) * 196 + w4];
    float4 v1 = src4[(size_t)(c0 + 1) * 196 + w4];
    float4 v2 = src4[(size_t)(c0 + 2) * 196 + w4];
    float4 v3 = src4[(size_t)(c0 + 3) * 196 + w4];
    f16x4 o0 = { (_Float16)v0.x, (_Float16)v1.x, (_Float16)v2.x, (_Float16)v3.x };
    f16x4 o1 = { (_Float16)v0.y, (_Float16)v1.y, (_Float16)v2.y, (_Float16)v3.y };
    f16x4 o2 = { (_Float16)v0.z, (_Float16)v1.z, (_Float16)v2.z, (_Float16)v3.z };
    f16x4 o3 = { (_Float16)v0.w, (_Float16)v1.w, (_Float16)v2.w, (_Float16)v3.w };
    *(f16x4*)&tile[w4 * 4 + 0][c0] = o0;
    *(f16x4*)&tile[w4 * 4 + 1][c0] = o1;
    *(f16x4*)&tile[w4 * 4 + 2][c0] = o2;
    *(f16x4*)&tile[w4 * 4 + 3][c0] = o3;
  }
  __syncthreads();

  // stats: 16 lanes per position, each lane sums a contiguous 48-channel slab
  if (tid < WW * 16) {
    int w = tid >> 4, j = tid & 15;
    float s = 0.f, ss = 0.f;
    const _Float16* row = &tile[w][j * 48];
#pragma unroll
    for (int k = 0; k < 6; ++k) {
      f16x8 v = *(const f16x8*)(row + k * 8);
#pragma unroll
      for (int u = 0; u < 8; ++u) { float f = (float)v[u]; s += f; ss += f * f; }
    }
#pragma unroll
    for (int d = 8; d; d >>= 1) {
      s += __shfl_down(s, d, 16);
      ss += __shfl_down(ss, d, 16);
    }
    if (j == 0) {
      float mu = s * (1.f / 768.f);
      float var = ss * (1.f / 768.f) - mu * mu;
      s_mean[w] = mu;
      s_rstd[w] = rsqrtf(var + 1e-6f);
    }
  }
  __syncthreads();

  // normalize + mask fill: f16x8 in, f16x8 out (16B coalesced global stores)
  for (int i = tid; i < WW * 96; i += 512) {
    int w = i / 96, q = i - w * 96;
    int c0 = q * 8;
    f16x8 o;
    if (s_act[w]) {
      f16x8 v = *(const f16x8*)&tile[w][c0];
      float mu = s_mean[w], rs = s_rstd[w];
#pragma unroll
      for (int u = 0; u < 8; ++u)
        o[u] = (_Float16)(((float)v[u] - mu) * rs * s_gamma[c0 + u] + s_beta[c0 + u]);
    } else {
      o = *(const f16x8*)&s_mt[c0];
    }
    *(f16x8*)(xrow + (size_t)(w + 1) * CE + c0) = o;
  }
}

// ---------------- kernel 3: strip implicit-GEMM conv (unchanged) ----------------
// M' = padded pixel space (57600). Tile: 128 padded rows x 64 cols.
// Outer loop: 24 ci-chunks of 32. Per chunk: stage A window (192 pixels x 64B,
// serves ALL 9 taps via tap-shifted LDS reads) + B for all 9 taps (36 KB).
// 36 MFMA per barrier-pair per wave. nb = blockIdx&7 pins each XCD to one
// 884 KB B panel -> L2-resident B.
#define GLDS(src, dst) __builtin_amdgcn_global_load_lds( \
    (const __attribute__((address_space(1))) void*)(src), \
    (__attribute__((address_space(3))) void*)(dst), 16, 0, 0)

__global__ void __launch_bounds__(512) conv_strip_kernel(
    const _Float16* __restrict__ xp, const _Float16* __restrict__ wT,
    const float* __restrict__ bias, float* __restrict__ out) {
  __shared__ _Float16 smem[24576];    // A: 192*64B = 12 KB | B: 9*4 KB = 36 KB
  char* sAb = (char*)smem;
  char* sBb = sAb + 12288;

  const int t = threadIdx.x;
  const int lane = t & 63, wv = t >> 6;
  const int nb = blockIdx.x & 7;            // XCD-pinned n panel
  const int mb = blockIdx.x >> 3;
  const int p0 = mb * 128;
  const int n0 = nb * 64;

  // ---- staging maps (slot s -> LDS byte s*16; source chunk XOR-swizzled) ----
  const int jj = (t & 3) ^ ((t >> 3) & 3);  // source k-chunk 0..3
  const int pixA = t >> 2;                  // A pixels 0..127 (round0), +128 (round1)
  const _Float16* pA0 = xp + (size_t)(p0 + pixA) * CE + jj * 8;
  const _Float16* pA1 = pA0 + (size_t)128 * CE;
  const int rowB = (t >> 2) & 63;
  const int hiB = t >> 8;                   // 0/1
  const _Float16* pB = wT + (size_t)(n0 + rowB) * K_TOT + jj * 8;
  char* dA0 = sAb + wv * 1024;
  char* dA1 = sAb + 8192 + wv * 1024;
  char* dB0 = sBb + wv * 1024;

  // ---- fragment maps ----
  const int wm = wv >> 1, wn = wv & 1;      // 4 x 2 wave grid, wave = 32m x 32n
  const int rowbase0 = wm * 32 + (lane & 15);
  const int lq = lane >> 4;
  const int bfrag_off = (wn * 32 + (lane & 15)) * 64 +
                        ((lq ^ (((lane & 15) >> 1) & 3)) * 16);

  f32x4 acc[2][2] = {};
  const int tap_off[9] = {0, 1, 2, 30, 31, 32, 60, 61, 62};

  for (int c24 = 0; c24 < 24; ++c24) {
    const int koff = c24 * 32;  // halfs
    GLDS(pA0 + koff, dA0);
    if (wv < 4) GLDS(pA1 + koff, dA1);
#pragma unroll
    for (int k = 0; k < 4; ++k)
      GLDS(pB + (2 * k + hiB) * CE + koff, dB0 + 8192 * k);
    if (wv < 4) GLDS(pB + 8 * CE + koff, dB0 + 32768);
    __syncthreads();

#pragma unroll
    for (int tap = 0; tap < 9; ++tap) {
      const int rA = rowbase0 + tap_off[tap];
      const char* aptr = sAb + rA * 64 + ((lq ^ ((rA >> 1) & 3)) * 16);
      f16x8 a0 = *(const f16x8*)(aptr);
      f16x8 a1 = *(const f16x8*)(aptr + 1024);
      const char* bptr = sBb + tap * 4096 + bfrag_off;
      f16x8 b0 = *(const f16x8*)(bptr);
      f16x8 b1 = *(const f16x8*)(bptr + 1024);
      acc[0][0] = __builtin_amdgcn_mfma_f32_16x16x32_f16(a0, b0, acc[0][0], 0, 0, 0);
      acc[0][1] = __builtin_amdgcn_mfma_f32_16x16x32_f16(a0, b1, acc[0][1], 0, 0, 0);
      acc[1][0] = __builtin_amdgcn_mfma_f32_16x16x32_f16(a1, b0, acc[1][0], 0, 0, 0);
      acc[1][1] = __builtin_amdgcn_mfma_f32_16x16x32_f16(a1, b1, acc[1][1], 0, 0, 0);
    }
    __syncthreads();
  }

  // ---- epilogue: mask pad rows, f32x4 fast path ----
  float bv[2];
#pragma unroll
  for (int ni = 0; ni < 2; ++ni) bv[ni] = bias[n0 + wn * 32 + ni * 16 + (lane & 15)];
#pragma unroll
  for (int mi = 0; mi < 2; ++mi) {
    int g = p0 + wm * 32 + mi * 16 + (lane >> 4) * 4;  // 4-aligned padded index
    int b = g / 900;
    int q = g - b * 900;
    int ph = q / 30, pw = q - ph * 30;                 // pw even
#pragma unroll
    for (int ni = 0; ni < 2; ++ni) {
      int co = n0 + wn * 32 + ni * 16 + (lane & 15);
      f32x4 v = acc[mi][ni];
      v += bv[ni];
      float* obase = out + ((size_t)b * CD + co) * POS;
      if (b < NB && ph < 28) {
        if (pw <= 24) {
          *(f32x4*)(obase + ph * 28 + pw) = v;
        } else if (pw == 26) {
          obase[ph * 28 + 26] = v[0];
          obase[ph * 28 + 27] = v[1];
        }
      }
      if (pw == 28) {      // elements r=2,3 roll into next image row (maybe next b)
        int b2 = b, ph2 = ph + 1;
        if (ph2 == 30) { b2++; ph2 = 0; }
        if (b2 < NB && ph2 < 28) {
          float* o2 = out + ((size_t)b2 * CD + co) * POS + ph2 * 28;
          o2[0] = v[2];
          o2[1] = v[3];
        }
      }
    }
  }
}

extern "C" void kernel_launch(void* const* d_in, const int* in_sizes, int n_in,
                              void* d_out, int out_size, void* d_ws, size_t ws_size,
                              hipStream_t stream) {
  const float* bcff = (const float*)d_in[0];
  const int* cur_active = (const int*)d_in[1];
  const float* mask_token = (const float*)d_in[2];
  const float* ln_w = (const float*)d_in[3];
  const float* ln_b = (const float*)d_in[4];
  const float* conv_w = (const float*)d_in[5];
  const float* conv_b = (const float*)d_in[6];
  float* out = (float*)d_out;

  char* ws = (char*)d_ws;
  _Float16* xp = (_Float16*)ws;                       // XP_PIX*768*2 = 88,670,208 B
  _Float16* wT = (_Float16*)(ws + (size_t)XP_PIX * CE * 2);  // 7,077,888 B

  prep_w_kernel<<<dim3(CD), dim3(256), 0, stream>>>(conv_w, wT);
  ln_fused_kernel<<<dim3(NB * HP), dim3(512), 0, stream>>>(bcff, cur_active, mask_token,
                                                           ln_w, ln_b, xp);
  // 450 m-blocks x 8 n-blocks; nb = blockIdx & 7 -> one B panel per XCD
  conv_strip_kernel<<<dim3(450 * 8), dim3(512), 0, stream>>>(xp, wT, conv_b, out);
}